// Round 13
// baseline (1478.581 us; speedup 1.0000x reference)
//
#include <hip/hip_runtime.h>
#include <stdint.h>

#define B_ 1024
#define F_ 4
#define M_ 512
#define D_ 8192
#define ITERS_ 10
#define DW_ 128      // D/64 u64 words per D-vector
#define BUFSZ 49152  // one ring buffer: Aq 8K + Ar 8K + B(512x64) 32K

typedef unsigned long long u64;
typedef unsigned int u32;
typedef unsigned short u16;
typedef signed char i8;

typedef int i32x4 __attribute__((ext_vector_type(4)));
typedef u64 u64x2 __attribute__((ext_vector_type(2)));

struct Flags { u32 done; u32 k; u32 conv[ITERS_]; };

__device__ inline void gload_lds16(const void* g, void* l){
  __builtin_amdgcn_global_load_lds(
      (const __attribute__((address_space(1))) void*)g,
      (__attribute__((address_space(3))) void*)l, 16, 0, 0);
}

__device__ inline bool conv_prefix_done(const u32* conv, int iter){
  bool d = false;
  for (int j = 0; j < iter; ++j) d |= (conv[j] != 0u);
  return d;
}

// sign-bit pack (bit=1 => negative) via wave ballot; one u64 per 64 floats
__global__ void k_bitify(const float* __restrict__ src, u64* __restrict__ dst){
  long gid = (long)blockIdx.x * 256 + threadIdx.x;
  float v = src[gid];
  u64 m = __ballot(v < 0.0f);
  if ((threadIdx.x & 63) == 0) dst[gid >> 6] = m;
}

// init_est is broadcast over b by construction; bitify row b=0 only + Flags init
__global__ void k_bitify0(const float* __restrict__ init_est, u64* __restrict__ tmp0,
                          Flags* fl){
  long gid = (long)blockIdx.x * 256 + threadIdx.x;   // over F_*D_
  float v = init_est[gid];
  u64 m = __ballot(v < 0.0f);
  if ((threadIdx.x & 63) == 0) tmp0[gid >> 6] = m;
  if (blockIdx.x == 0){
    if (threadIdx.x == 0){ fl->done = 0; fl->k = 0; }
    if (threadIdx.x < ITERS_) fl->conv[threadIdx.x] = 1u;
  }
}

// broadcast tmp0[f][w] to estbits[b][f][w] for all b
__global__ void k_bcast(const u64* __restrict__ tmp0, u64* __restrict__ estbits){
  long gid = (long)blockIdx.x * 256 + threadIdx.x;   // over B_*F_*DW_
  estbits[gid] = tmp0[gid & (F_*DW_ - 1)];
}

// one pass over cb: cbbT[f][w][m] (bit-packed) AND cbT8[f][d][m] (i8 +-1)
__global__ void k_cb_prep(const float* __restrict__ cb, u64* __restrict__ cbbT,
                          i8* __restrict__ cbT8){
  __shared__ i8 tile[64][68];
  int bx = blockIdx.x;
  int f = bx >> 10;
  int r = bx & 1023;
  int mt = r >> 7, dt = r & 127;
  for (int it = 0; it < 16; ++it){
    int lid = threadIdx.x + it*256;
    int i = lid >> 6, j = lid & 63;   // i = m-local (wave-uniform), j = d-local = lane
    float v = cb[((long)(f*M_ + mt*64 + i))*D_ + dt*64 + j];
    tile[j][i] = (v < 0.0f) ? (i8)-1 : (i8)1;
    u64 msk = __ballot(v < 0.0f);     // bit L = sign at d = dt*64 + L
    if (j == 0) cbbT[((long)(f*DW_ + dt))*M_ + mt*64 + i] = msk;
  }
  __syncthreads();
  for (int it = 0; it < 4; ++it){
    int lid = threadIdx.x + it*256;   // 1024 jobs: 64 d x 16 m-groups
    int dd = lid >> 4, mg = lid & 15;
    u32 p = (u32)(unsigned char)tile[dd][mg*4+0]
          | ((u32)(unsigned char)tile[dd][mg*4+1] << 8)
          | ((u32)(unsigned char)tile[dd][mg*4+2] << 16)
          | ((u32)(unsigned char)tile[dd][mg*4+3] << 24);
    *(u32*)(cbT8 + ((long)(f*D_ + dt*64 + dd))*M_ + mt*64 + mg*4) = p;
  }
}

// forward v2 (frozen best): nb = in ^ (xor of other three est);
// v[m] = 4096 - popc(nb ^ cb[m]). 1024 blocks, 256 threads. Occupancy curve
// measured R8-R10: 16 waves/CU optimal. ~33us/dispatch (R12 profile).
__global__ __launch_bounds__(256) void k_forward2(
    const u64* __restrict__ inbits, const u64* __restrict__ estbits,
    const u64* __restrict__ cbbT, i8* __restrict__ Aq, i8* __restrict__ Ar,
    const Flags* __restrict__ fl, int iter){
  if (conv_prefix_done(fl->conv, iter)) return;
  __shared__ u64 nbs[DW_][10];   // [w][bb], pad 10 (16B-aligned bb-pairs)
  int id = blockIdx.x;
  int rr = id & 7;
  int f   = rr & 3;
  int btl = rr >> 2;
  int q   = id >> 3;
  int bth = q & 63;
  int mh  = q >> 6;              // 0..1
  int bt  = bth*2 + btl;         // 0..127
  int b0  = bt * 8;
  int tid = threadIdx.x;
  for (int idx = tid; idx < 8*DW_; idx += 256){
    int w = idx & 127, bb = idx >> 7;
    const u64* eb = estbits + (long)(b0 + bb)*F_*DW_;
    u64 all = eb[w] ^ eb[DW_+w] ^ eb[2*DW_+w] ^ eb[3*DW_+w];
    nbs[w][bb] = inbits[(long)(b0 + bb)*DW_ + w] ^ all ^ eb[f*DW_ + w];
  }
  __syncthreads();
  int m = mh*256 + tid;
  int acc[8];
  #pragma unroll
  for (int bb = 0; bb < 8; ++bb) acc[bb] = 0;
  const u64* cbf = cbbT + (long)f*DW_*M_ + m;
  #pragma unroll 2
  for (int w = 0; w < DW_; ++w){
    u64 c = cbf[(long)w*M_];
    u64x2 n01 = *(const u64x2*)&nbs[w][0];
    u64x2 n23 = *(const u64x2*)&nbs[w][2];
    u64x2 n45 = *(const u64x2*)&nbs[w][4];
    u64x2 n67 = *(const u64x2*)&nbs[w][6];
    acc[0] += (int)__popcll(n01.x ^ c);
    acc[1] += (int)__popcll(n01.y ^ c);
    acc[2] += (int)__popcll(n23.x ^ c);
    acc[3] += (int)__popcll(n23.y ^ c);
    acc[4] += (int)__popcll(n45.x ^ c);
    acc[5] += (int)__popcll(n45.y ^ c);
    acc[6] += (int)__popcll(n67.x ^ c);
    acc[7] += (int)__popcll(n67.y ^ c);
  }
  #pragma unroll
  for (int bb = 0; bb < 8; ++bb){
    int v = 4096 - acc[bb];
    int r = ((v + 32) & 63) - 32;
    int qd = (v - r) >> 6;
    long base = ((long)(f*B_ + b0 + bb))*M_ + m;
    Aq[base] = (i8)qd;
    Ar[base] = (i8)r;
  }
}

// backward v4 (d512 + 3-buffer ring + counted vmcnt): the R12 profile showed
// the d256 kernel at 97us with MfmaUtil 13.6%, all pipes <21% busy — pure
// phase serialization from the depth-1 prefetch + vmcnt(0) drain at each
// __syncthreads. Fix = m201's counted-vmcnt pattern, which IS cross-wave
// safe (per-wave counted wait -> barrier propagates oldest-load completion);
// R7's failure was 2 buffers with same-parity overwrite, fixed by a 3-buffer
// ring (3 x 48KB, dynamic LDS 144KB, 1 block/CU x 8 waves).
//   - block = 512 threads, wave (wr=wv&3, wc=wv>>2): wr owns rows wr*32..+32,
//     wc owns d-half wc*256..+256 -> per-wave structure IDENTICAL to the
//     proven d256 kernel (acc[2][16], 20 ds_reads, 64 MFMA per phase).
//   - per phase: vmcnt(6) [kt's 6 done, kt+1's 6 in flight; NEVER 0 until
//     the last phase] -> s_barrier -> issue kt+2 into buf (kt+2)%3 -> compute.
//   - ring safety: buf (kt+2)%3 == (kt-1)%3, last read in phase kt-1; all
//     waves' reads retired before this phase's barrier (compiler lgkmcnt
//     precedes each MFMA consumption), so the overwrite cannot race.
// f-partitioned XCD grid: id%8 = f*2 + d-half; per-XCD footprint 3MB < L2.
__global__ __launch_bounds__(512, 2) void k_backward_d512(
    const i8* __restrict__ Aq, const i8* __restrict__ Ar, const i8* __restrict__ cbT8,
    u64* __restrict__ estbits, Flags* fl, int iter){
  if (conv_prefix_done(fl->conv, iter)) return;
  extern __shared__ __attribute__((aligned(16))) i8 smem[];   // 3*BUFSZ dynamic
  int id = blockIdx.x;
  int rr = id & 7;
  int f  = rr >> 1;
  int dh = rr & 1;
  int qq = id >> 3;           // 0..63
  int bt = qq & 7;
  int dtl= qq >> 3;           // 0..7
  int dtp= dh*8 + dtl;        // 0..15 (512-wide d tiles)
  int b0 = bt*128, d0 = dtp*512;
  int tid = threadIdx.x;
  int wv = tid >> 6, lane = tid & 63, l16 = lane & 15, quad = lane >> 4;
  int wr = wv & 3, wc = wv >> 2;       // row-group 0..3, d-half 0..1
  int rl = lane >> 2, pl = lane & 3;   // DMA: 4 lanes per 64B row

  i32x4 zero = {0, 0, 0, 0};
  i32x4 acc[2][16];
  #pragma unroll
  for (int i = 0; i < 2; ++i)
    #pragma unroll
    for (int j = 0; j < 16; ++j) acc[i][j] = zero;

  const i8* Aqg = Aq + ((long)f*B_ + b0)*M_;
  const i8* Arg = Ar + ((long)f*B_ + b0)*M_;
  const i8* Bg  = cbT8 + ((long)f*D_ + d0)*M_;

  // DMA plan per phase: 48 jobs = Aq 8 + Ar 8 + B 32 windows (16 rows x 64B
  // = 1KB each); wave takes 6. lane fetches chunk (pl ^ swz) so LDS slot c'
  // holds chunk c'^swz (matches read-side swizzle; (row>>1)&3 == (rl>>1)&3
  // since windows are 16-row aligned).
  int swz = (rl >> 1) & 3;
  const i8* gsrc[6]; int lbase[6];
  #pragma unroll
  for (int j2 = 0; j2 < 6; ++j2){
    int job = j2*8 + wv;            // 0..47
    const i8* src; int lb; int jj;
    if (job < 8)      { src = Aqg; jj = job;      lb =         jj*1024; }
    else if (job < 16){ src = Arg; jj = job - 8;  lb =  8192 + jj*1024; }
    else              { src = Bg;  jj = job - 16; lb = 16384 + jj*1024; }
    gsrc[j2]  = src + (long)(jj*16 + rl)*M_ + ((pl ^ swz) << 4);
    lbase[j2] = lb;                 // HW adds lane*16B
  }

#define ISSUE_KT(KT) do{ \
    i8* ba_ = smem + ((KT) % 3) * BUFSZ; const int k0_ = (KT)*64; \
    _Pragma("unroll") \
    for (int j2_ = 0; j2_ < 6; ++j2_) \
      gload_lds16(gsrc[j2_] + k0_, ba_ + lbase[j2_]); \
  }while(0)

  // prologue: stage kt0, kt1 (12 outstanding per wave)
  ISSUE_KT(0);
  ISSUE_KT(1);

  #pragma unroll
  for (int kt = 0; kt < 8; ++kt){
    if (kt < 7) asm volatile("s_waitcnt vmcnt(6)" ::: "memory");
    else        asm volatile("s_waitcnt vmcnt(0)" ::: "memory");
    __builtin_amdgcn_s_barrier();
    asm volatile("" ::: "memory");
    __builtin_amdgcn_sched_barrier(0);
    if (kt < 6) ISSUE_KT(kt + 2);

    const i8* sb = smem + (kt % 3) * BUFSZ;
    i32x4 aq[2], ar[2];
    #pragma unroll
    for (int rt = 0; rt < 2; ++rt){
      int row = wr*32 + rt*16 + l16;     // A[m=lane&15][k=quad*16+j]
      int c = (quad ^ ((row >> 1) & 3)) << 4;
      aq[rt] = *(const i32x4*)(sb +        row*64 + c);
      ar[rt] = *(const i32x4*)(sb + 8192 + row*64 + c);
    }
    #pragma unroll
    for (int ctl = 0; ctl < 16; ++ctl){
      int rowB = wc*256 + ctl*16 + l16;  // B[k=quad*16+j][n=lane&15] via B^T
      int c = (quad ^ ((rowB >> 1) & 3)) << 4;
      i32x4 bb = *(const i32x4*)(sb + 16384 + rowB*64 + c);
      i32x4 bb64;
      #pragma unroll
      for (int g = 0; g < 4; ++g)
        bb64[g] = (int)(((u32)bb[g] << 6) & 0xC0C0C0C0u);   // 64*c, exact for c=+-1
      acc[0][ctl] = __builtin_amdgcn_mfma_i32_16x16x64_i8(aq[0], bb64, acc[0][ctl], 0, 0, 0);
      acc[0][ctl] = __builtin_amdgcn_mfma_i32_16x16x64_i8(ar[0], bb,   acc[0][ctl], 0, 0, 0);
      acc[1][ctl] = __builtin_amdgcn_mfma_i32_16x16x64_i8(aq[1], bb64, acc[1][ctl], 0, 0, 0);
      acc[1][ctl] = __builtin_amdgcn_mfma_i32_16x16x64_i8(ar[1], bb,   acc[1][ctl], 0, 0, 0);
    }
  }
#undef ISSUE_KT

  // ballot epilogue (proven d256 scheme + wc*4 word offset): C/D layout
  // col=lane&15, row=quad*4+reg. Wave covers rows wr*32+rt*16+[0,16) x
  // d-words wc*4+[0,4). Lane<16 holds word pw=lane&3 of row-quad q3=lane>>2.
  int q3 = (lane >> 2) & 3, pw = lane & 3;
  int pw1 = pw & 1, pw2 = pw >> 1;
  u64 wreg[2][4];
  #pragma unroll
  for (int rt = 0; rt < 2; ++rt){
    #pragma unroll
    for (int r = 0; r < 4; ++r){
      u64 g0[4], g1[4], g2[4], g3[4];
      #pragma unroll
      for (int c = 0; c < 4; ++c){
        g0[c] = __ballot(acc[rt][c][r]      < 0);
        g1[c] = __ballot(acc[rt][4 + c][r]  < 0);
        g2[c] = __ballot(acc[rt][8 + c][r]  < 0);
        g3[c] = __ballot(acc[rt][12 + c][r] < 0);
      }
      u64 word = 0;
      #pragma unroll
      for (int c = 0; c < 4; ++c){
        u64 s = pw2 ? (pw1 ? g3[c] : g2[c]) : (pw1 ? g1[c] : g0[c]);
        word |= ((s >> (16*q3)) & 0xFFFFull) << (16*c);
      }
      wreg[rt][r] = word;
    }
  }
  u64 oldv[2][4];
  if (lane < 16){
    #pragma unroll
    for (int rt = 0; rt < 2; ++rt)
      #pragma unroll
      for (int r = 0; r < 4; ++r){
        int row = wr*32 + rt*16 + q3*4 + r;
        oldv[rt][r] = estbits[((long)(b0 + row)*F_ + f)*DW_ + dtp*8 + wc*4 + pw];
      }
  }
  u32 flag = 0;
  if (lane < 16){
    #pragma unroll
    for (int rt = 0; rt < 2; ++rt)
      #pragma unroll
      for (int r = 0; r < 4; ++r){
        int row = wr*32 + rt*16 + q3*4 + r;
        long addr = ((long)(b0 + row)*F_ + f)*DW_ + dtp*8 + wc*4 + pw;
        estbits[addr] = wreg[rt][r];
        flag |= (oldv[rt][r] != wreg[rt][r]) ? 1u : 0u;
      }
  }
  u32 mymiss = (u32)(__ballot(flag != 0) != 0ull);
  if (lane == 0 && mymiss) atomicAnd(&fl->conv[iter], 0u);
}

// final: outcome = argmax_m |sim|, first-occurrence ties (exact integers).
__global__ __launch_bounds__(256) void k_outcome(
    const u64* __restrict__ estbits, const u64* __restrict__ cbbT,
    const Flags* __restrict__ fl, float* __restrict__ out){
  __shared__ u64 es[8][DW_];
  __shared__ int redv[4][8], redi[4][8];
  int f = blockIdx.y, b0 = blockIdx.x * 8;
  int tid = threadIdx.x, wv = tid >> 6, lane = tid & 63;
  for (int idx = tid; idx < 8*DW_; idx += 256){
    int bb = idx >> 7, w = idx & 127;
    es[bb][w] = estbits[((long)(b0 + bb)*F_ + f)*DW_ + w];
  }
  __syncthreads();
  const u64* cbf = cbbT + (long)f*DW_*M_;
  int m0 = tid, m1 = tid + 256;
  int acc0[8], acc1[8];
  #pragma unroll
  for (int bb = 0; bb < 8; ++bb){ acc0[bb] = 0; acc1[bb] = 0; }
  for (int w = 0; w < DW_; ++w){
    u64 c0 = cbf[(long)w*M_ + m0];
    u64 c1 = cbf[(long)w*M_ + m1];
    #pragma unroll
    for (int bb = 0; bb < 8; ++bb){
      u64 e = es[bb][w];
      acc0[bb] += (int)__popcll(e ^ c0);
      acc1[bb] += (int)__popcll(e ^ c1);
    }
  }
  int bv[8], bi[8];
  #pragma unroll
  for (int bb = 0; bb < 8; ++bb){
    int a0 = 4096 - acc0[bb]; if (a0 < 0) a0 = -a0;
    int a1 = 4096 - acc1[bb]; if (a1 < 0) a1 = -a1;
    bv[bb] = a0; bi[bb] = m0;
    if (a1 > a0){ bv[bb] = a1; bi[bb] = m1; }   // tie keeps lower m
  }
  for (int off = 32; off; off >>= 1){
    #pragma unroll
    for (int bb = 0; bb < 8; ++bb){
      int ov = __shfl_xor(bv[bb], off, 64);
      int oi = __shfl_xor(bi[bb], off, 64);
      if (ov > bv[bb] || (ov == bv[bb] && oi < bi[bb])){ bv[bb] = ov; bi[bb] = oi; }
    }
  }
  if (lane == 0)
    #pragma unroll
    for (int bb = 0; bb < 8; ++bb){ redv[wv][bb] = bv[bb]; redi[wv][bb] = bi[bb]; }
  __syncthreads();
  if (tid < 8){
    int v0 = redv[0][tid], i0 = redi[0][tid];
    for (int w = 1; w < 4; ++w){
      int v = redv[w][tid], i = redi[w][tid];
      if (v > v0 || (v == v0 && i < i0)){ v0 = v; i0 = i; }
    }
    out[(long)(b0 + tid)*F_ + f] = (float)i0;
  }
  if (blockIdx.x == 0 && f == 0 && tid == 0){
    int k = ITERS_;
    for (int j = 0; j < ITERS_; ++j) if (fl->conv[j]){ k = j + 1; break; }
    out[B_*F_] = (float)k;
  }
}

__global__ void k_unpack(const u64* __restrict__ estbits, float* __restrict__ out){
  long gid = (long)blockIdx.x*256 + threadIdx.x;   // over B*F*D/4
  int bf = (int)(gid >> 11);
  int d4 = (int)(gid & 2047);
  u64 word = estbits[(long)bf*DW_ + (d4 >> 4)];
  u32 nib = (u32)(word >> ((d4 & 15) * 4)) & 0xFu;
  long base = (long)(B_*F_ + 1) + (long)bf*D_ + (long)d4*4;
  out[base+0] = (nib & 1u) ? -1.0f : 1.0f;
  out[base+1] = (nib & 2u) ? -1.0f : 1.0f;
  out[base+2] = (nib & 4u) ? -1.0f : 1.0f;
  out[base+3] = (nib & 8u) ? -1.0f : 1.0f;
}

extern "C" void kernel_launch(void* const* d_in, const int* in_sizes, int n_in,
                              void* d_out, int out_size, void* d_ws, size_t ws_size,
                              hipStream_t stream){
  const float* input    = (const float*)d_in[0];
  const float* init_est = (const float*)d_in[1];
  const float* cb       = (const float*)d_in[2];
  char* ws   = (char*)d_ws;
  char* outc = (char*)d_out;

  static int s_attr = 0;
  if (!s_attr){
    hipFuncSetAttribute((const void*)k_backward_d512,
                        hipFuncAttributeMaxDynamicSharedMemorySize, 3*BUFSZ);
    s_attr = 1;
  }

  size_t off = 0;
  Flags* fl = (Flags*)(ws); off = 1024;
  u64* tmp0    = (u64*)(ws + off); off += (size_t)F_*DW_*8;        // 4 KB
  off = (off + 1023) & ~size_t(1023);
  u64* inbits  = (u64*)(ws + off); off += (size_t)B_*DW_*8;        // 1 MB
  u64* estbits = (u64*)(ws + off); off += (size_t)B_*F_*DW_*8;     // 4 MB
  u64* cbbT    = (u64*)(ws + off); off += (size_t)F_*DW_*M_*8;     // 2 MB
  size_t big = (size_t)F_*D_*M_ + 2*(size_t)F_*B_*M_;              // 16 MB + 4 MB
  i8 *cbT8, *Aq, *Ar;
  if (ws_size >= off + big + 1024){
    cbT8 = (i8*)(ws + off); off += (size_t)F_*D_*M_;
    Aq   = (i8*)(ws + off); off += (size_t)F_*B_*M_;
    Ar   = (i8*)(ws + off); off += (size_t)F_*B_*M_;
  } else {
    // d_out is 33558529 float32 = 128.02 MiB; est chunk spans [16388, 134234116).
    // Park scratch high — only the final k_unpack overwrites it, after last use.
    cbT8 = (i8*)(outc + (80ull << 20));    // 80..96 MiB
    Aq   = (i8*)(outc + (100ull << 20));   // 100..102 MiB
    Ar   = (i8*)(outc + (104ull << 20));   // 104..106 MiB
  }

  k_bitify0<<<(F_*D_)/256, 256, 0, stream>>>(init_est, tmp0, fl);
  k_bcast<<<(B_*F_*DW_)/256, 256, 0, stream>>>(tmp0, estbits);
  k_bitify<<<(B_*(long)D_)/256, 256, 0, stream>>>(input, inbits);
  k_cb_prep<<<4096, 256, 0, stream>>>(cb, cbbT, cbT8);

  for (int it = 0; it < ITERS_; ++it){
    k_forward2<<<1024, 256, 0, stream>>>(inbits, estbits, cbbT, Aq, Ar, fl, it);
    k_backward_d512<<<512, 512, 3*BUFSZ, stream>>>(Aq, Ar, cbT8, estbits, fl, it);
  }

  k_outcome<<<dim3(B_/8, F_), 256, 0, stream>>>(estbits, cbbT, fl, (float*)d_out);
  k_unpack<<<((long)B_*F_*D_/4)/256, 256, 0, stream>>>(estbits, (float*)d_out);
}

// Round 14
// 1396.120 us; speedup vs baseline: 1.0591x; 1.0591x over previous
//
#include <hip/hip_runtime.h>
#include <stdint.h>

#define B_ 1024
#define F_ 4
#define M_ 512
#define D_ 8192
#define ITERS_ 10
#define DW_ 128      // D/64 u64 words per D-vector

typedef unsigned long long u64;
typedef unsigned int u32;
typedef unsigned short u16;
typedef signed char i8;

typedef int i32x4 __attribute__((ext_vector_type(4)));
typedef u64 u64x2 __attribute__((ext_vector_type(2)));

struct Flags { u32 done; u32 k; u32 conv[ITERS_]; };

__device__ inline void gload_lds16(const void* g, void* l){
  __builtin_amdgcn_global_load_lds(
      (const __attribute__((address_space(1))) void*)g,
      (__attribute__((address_space(3))) void*)l, 16, 0, 0);
}

__device__ inline bool conv_prefix_done(const u32* conv, int iter){
  bool d = false;
  for (int j = 0; j < iter; ++j) d |= (conv[j] != 0u);
  return d;
}

// sign-bit pack (bit=1 => negative) via wave ballot; one u64 per 64 floats
__global__ void k_bitify(const float* __restrict__ src, u64* __restrict__ dst){
  long gid = (long)blockIdx.x * 256 + threadIdx.x;
  float v = src[gid];
  u64 m = __ballot(v < 0.0f);
  if ((threadIdx.x & 63) == 0) dst[gid >> 6] = m;
}

// init_est is broadcast over b by construction; bitify row b=0 only + Flags init
__global__ void k_bitify0(const float* __restrict__ init_est, u64* __restrict__ tmp0,
                          Flags* fl){
  long gid = (long)blockIdx.x * 256 + threadIdx.x;   // over F_*D_
  float v = init_est[gid];
  u64 m = __ballot(v < 0.0f);
  if ((threadIdx.x & 63) == 0) tmp0[gid >> 6] = m;
  if (blockIdx.x == 0){
    if (threadIdx.x == 0){ fl->done = 0; fl->k = 0; }
    if (threadIdx.x < ITERS_) fl->conv[threadIdx.x] = 1u;
  }
}

// broadcast tmp0[f][w] to estbits[b][f][w] for all b
__global__ void k_bcast(const u64* __restrict__ tmp0, u64* __restrict__ estbits){
  long gid = (long)blockIdx.x * 256 + threadIdx.x;   // over B_*F_*DW_
  estbits[gid] = tmp0[gid & (F_*DW_ - 1)];
}

// one pass over cb: cbbT[f][w][m] (bit-packed) AND cbT8[f][d][m] (i8 +-1)
__global__ void k_cb_prep(const float* __restrict__ cb, u64* __restrict__ cbbT,
                          i8* __restrict__ cbT8){
  __shared__ i8 tile[64][68];
  int bx = blockIdx.x;
  int f = bx >> 10;
  int r = bx & 1023;
  int mt = r >> 7, dt = r & 127;
  for (int it = 0; it < 16; ++it){
    int lid = threadIdx.x + it*256;
    int i = lid >> 6, j = lid & 63;   // i = m-local (wave-uniform), j = d-local = lane
    float v = cb[((long)(f*M_ + mt*64 + i))*D_ + dt*64 + j];
    tile[j][i] = (v < 0.0f) ? (i8)-1 : (i8)1;
    u64 msk = __ballot(v < 0.0f);     // bit L = sign at d = dt*64 + L
    if (j == 0) cbbT[((long)(f*DW_ + dt))*M_ + mt*64 + i] = msk;
  }
  __syncthreads();
  for (int it = 0; it < 4; ++it){
    int lid = threadIdx.x + it*256;   // 1024 jobs: 64 d x 16 m-groups
    int dd = lid >> 4, mg = lid & 15;
    u32 p = (u32)(unsigned char)tile[dd][mg*4+0]
          | ((u32)(unsigned char)tile[dd][mg*4+1] << 8)
          | ((u32)(unsigned char)tile[dd][mg*4+2] << 16)
          | ((u32)(unsigned char)tile[dd][mg*4+3] << 24);
    *(u32*)(cbT8 + ((long)(f*D_ + dt*64 + dd))*M_ + mt*64 + mg*4) = p;
  }
}

// forward v2 (frozen best): nb = in ^ (xor of other three est);
// v[m] = 4096 - popc(nb ^ cb[m]). 1024 blocks, 256 threads. Occupancy curve
// measured R8-R10: 16 waves/CU optimal. ~33us/dispatch (R12 profile).
__global__ __launch_bounds__(256) void k_forward2(
    const u64* __restrict__ inbits, const u64* __restrict__ estbits,
    const u64* __restrict__ cbbT, i8* __restrict__ Aq, i8* __restrict__ Ar,
    const Flags* __restrict__ fl, int iter){
  if (conv_prefix_done(fl->conv, iter)) return;
  __shared__ u64 nbs[DW_][10];   // [w][bb], pad 10 (16B-aligned bb-pairs)
  int id = blockIdx.x;
  int rr = id & 7;
  int f   = rr & 3;
  int btl = rr >> 2;
  int q   = id >> 3;
  int bth = q & 63;
  int mh  = q >> 6;              // 0..1
  int bt  = bth*2 + btl;         // 0..127
  int b0  = bt * 8;
  int tid = threadIdx.x;
  for (int idx = tid; idx < 8*DW_; idx += 256){
    int w = idx & 127, bb = idx >> 7;
    const u64* eb = estbits + (long)(b0 + bb)*F_*DW_;
    u64 all = eb[w] ^ eb[DW_+w] ^ eb[2*DW_+w] ^ eb[3*DW_+w];
    nbs[w][bb] = inbits[(long)(b0 + bb)*DW_ + w] ^ all ^ eb[f*DW_ + w];
  }
  __syncthreads();
  int m = mh*256 + tid;
  int acc[8];
  #pragma unroll
  for (int bb = 0; bb < 8; ++bb) acc[bb] = 0;
  const u64* cbf = cbbT + (long)f*DW_*M_ + m;
  #pragma unroll 2
  for (int w = 0; w < DW_; ++w){
    u64 c = cbf[(long)w*M_];
    u64x2 n01 = *(const u64x2*)&nbs[w][0];
    u64x2 n23 = *(const u64x2*)&nbs[w][2];
    u64x2 n45 = *(const u64x2*)&nbs[w][4];
    u64x2 n67 = *(const u64x2*)&nbs[w][6];
    acc[0] += (int)__popcll(n01.x ^ c);
    acc[1] += (int)__popcll(n01.y ^ c);
    acc[2] += (int)__popcll(n23.x ^ c);
    acc[3] += (int)__popcll(n23.y ^ c);
    acc[4] += (int)__popcll(n45.x ^ c);
    acc[5] += (int)__popcll(n45.y ^ c);
    acc[6] += (int)__popcll(n67.x ^ c);
    acc[7] += (int)__popcll(n67.y ^ c);
  }
  #pragma unroll
  for (int bb = 0; bb < 8; ++bb){
    int v = 4096 - acc[bb];
    int r = ((v + 32) & 63) - 32;
    int qd = (v - r) >> 6;
    long base = ((long)(f*B_ + b0 + bb))*M_ + m;
    Aq[base] = (i8)qd;
    Ar[base] = (i8)r;
  }
}

// backward v5 (d256 + mixed-depth ring + counted vmcnt): IDENTICAL tile,
// grid, XCD map, epilogue, and write pattern to the verified R12 d256 kernel
// (97us, MfmaUtil 13.6%) — the ONLY change is the staging schedule. R12's
// per-phase __syncthreads compiled to vmcnt(0), draining the JUST-ISSUED
// next-tile batch every phase (full latency exposed 8x). R13 proved counted
// vmcnt works (+15% even at 1 blk/CU) but confounded it with a tile change.
// Here: A double-buffered (2x16KB, depth-1: issued phase kt, needed kt+1 —
// ~600cyc compute covers L2 latency) + B triple-buffered (3x16KB, depth-2)
// = 80KB exactly -> still 2 blocks/CU, 8 waves/CU.
// Ring safety (all after the phase-kt barrier): A[kt+1] overwrites buf
// (kt+1)&1=(kt-1)&1, B[kt+2] overwrites (kt+2)%3=(kt-1)%3 — both last read
// in phase kt-1, whose reads retired before this barrier.
// Queue (4 jobs/batch/wave): prologue A0,B0,B1; phase kt issues A[kt+1],
// B[kt+2]; at phase-top the two oldest batches (A[kt],B[kt]) must land ->
// s_waitcnt vmcnt(4) for kt 0..6 (B[kt+1] stays in flight), vmcnt(0) at 7.
// f-partitioned XCD grid: id%8 = f*2 + (d-half); 1024 blocks.
__global__ __launch_bounds__(256, 2) void k_backward_d256r(
    const i8* __restrict__ Aq, const i8* __restrict__ Ar, const i8* __restrict__ cbT8,
    u64* __restrict__ estbits, Flags* fl, int iter){
  if (conv_prefix_done(fl->conv, iter)) return;
  extern __shared__ __attribute__((aligned(16))) i8 smem[];  // 80KB dynamic
  int id = blockIdx.x;
  int rr = id & 7;
  int f  = rr >> 1;
  int dh = rr & 1;
  int qq = id >> 3;
  int bt = qq & 7;
  int dtl= qq >> 3;           // 0..15
  int dtp= dh*16 + dtl;       // 0..31 (256-wide d tiles)
  int b0 = bt*128, d0 = dtp*256;
  int tid = threadIdx.x;
  int wv = tid >> 6, lane = tid & 63, l16 = lane & 15, quad = lane >> 4;
  int rl = lane >> 2, pl = lane & 3;   // DMA: 4 lanes per 64B row

  i32x4 zero = {0, 0, 0, 0};
  i32x4 acc[2][16];
  #pragma unroll
  for (int i = 0; i < 2; ++i)
    #pragma unroll
    for (int j = 0; j < 16; ++j) acc[i][j] = zero;

  const i8* Aqg = Aq + ((long)f*B_ + b0)*M_;
  const i8* Arg = Ar + ((long)f*B_ + b0)*M_;
  const i8* Bg  = cbT8 + ((long)f*D_ + d0)*M_;

  // DMA plans. A-batch: 16 jobs (Aq rows 0..7 windows, Ar 8..15), wave takes
  // 4. B-batch: 16 jobs, wave takes 4. Each job = 16 rows x 64B = 1KB; lane
  // fetches chunk (pl ^ swz) so LDS slot c' holds chunk c'^swz (matches
  // read-side swizzle; window 16-row alignment keeps (row>>1)&3 == swz law).
  int swz = (rl >> 1) & 3;
  const i8* gA[4]; int lA[4]; const i8* gB[4]; int lB[4];
  #pragma unroll
  for (int j2 = 0; j2 < 4; ++j2){
    int job = j2*4 + wv;            // 0..15
    const i8* srcA = (job < 8) ? Aqg : Arg;
    int jj = job & 7;
    gA[j2] = srcA + (long)(jj*16 + rl)*M_ + ((pl ^ swz) << 4);
    lA[j2] = ((job < 8) ? 0 : 8192) + jj*1024;
    gB[j2] = Bg + (long)(job*16 + rl)*M_ + ((pl ^ swz) << 4);
    lB[j2] = job*1024;
  }

#define ISSUE_A(KT) do{ \
    i8* ba_ = smem + ((KT)&1)*16384; const int k0_ = (KT)*64; \
    _Pragma("unroll") \
    for (int j_ = 0; j_ < 4; ++j_) gload_lds16(gA[j_] + k0_, ba_ + lA[j_]); \
  }while(0)
#define ISSUE_B(KT) do{ \
    i8* bb_ = smem + 32768 + ((KT)%3)*16384; const int k0_ = (KT)*64; \
    _Pragma("unroll") \
    for (int j_ = 0; j_ < 4; ++j_) gload_lds16(gB[j_] + k0_, bb_ + lB[j_]); \
  }while(0)

  // prologue: A0, B0, B1 in flight (12 jobs/wave)
  ISSUE_A(0);
  ISSUE_B(0);
  ISSUE_B(1);

  #pragma unroll
  for (int kt = 0; kt < 8; ++kt){
    if (kt < 7) asm volatile("s_waitcnt vmcnt(4)" ::: "memory");
    else        asm volatile("s_waitcnt vmcnt(0)" ::: "memory");
    __builtin_amdgcn_s_barrier();
    asm volatile("" ::: "memory");
    __builtin_amdgcn_sched_barrier(0);
    if (kt + 1 < 8) ISSUE_A(kt + 1);
    if (kt + 2 < 8) ISSUE_B(kt + 2);

    const i8* sa  = smem + (kt & 1)*16384;
    const i8* sbB = smem + 32768 + (kt % 3)*16384;
    i32x4 aq[2], ar[2];
    #pragma unroll
    for (int rt = 0; rt < 2; ++rt){
      int row = wv*32 + rt*16 + l16;     // A[m=lane&15][k=quad*16+j]
      int c = (quad ^ ((row >> 1) & 3)) << 4;
      aq[rt] = *(const i32x4*)(sa +        row*64 + c);
      ar[rt] = *(const i32x4*)(sa + 8192 + row*64 + c);
    }
    #pragma unroll
    for (int ct = 0; ct < 16; ++ct){
      int rowB = ct*16 + l16;            // B[k=quad*16+j][n=lane&15] via B^T tile
      int c = (quad ^ ((rowB >> 1) & 3)) << 4;
      i32x4 bb = *(const i32x4*)(sbB + rowB*64 + c);
      i32x4 bb64;
      #pragma unroll
      for (int g = 0; g < 4; ++g)
        bb64[g] = (int)(((u32)bb[g] << 6) & 0xC0C0C0C0u);   // 64*c, exact for c=+-1
      acc[0][ct] = __builtin_amdgcn_mfma_i32_16x16x64_i8(aq[0], bb64, acc[0][ct], 0, 0, 0);
      acc[0][ct] = __builtin_amdgcn_mfma_i32_16x16x64_i8(ar[0], bb,   acc[0][ct], 0, 0, 0);
      acc[1][ct] = __builtin_amdgcn_mfma_i32_16x16x64_i8(aq[1], bb64, acc[1][ct], 0, 0, 0);
      acc[1][ct] = __builtin_amdgcn_mfma_i32_16x16x64_i8(ar[1], bb,   acc[1][ct], 0, 0, 0);
    }
  }
#undef ISSUE_A
#undef ISSUE_B

  // ballot epilogue (identical to verified R12 d256): C/D layout col=lane&15,
  // row=quad*4+reg. Row covers 256 d-cols = 4 u64 words. Lane<16 holds word
  // pw=lane&3 of row-quad q3=lane>>2. All sign-words computed first, then
  // batched old-estbits reads, one compare/write pass.
  int q3 = (lane >> 2) & 3, pw = lane & 3;
  int pw1 = pw & 1, pw2 = pw >> 1;
  u64 wreg[2][4];
  #pragma unroll
  for (int rt = 0; rt < 2; ++rt){
    #pragma unroll
    for (int r = 0; r < 4; ++r){
      u64 g0[4], g1[4], g2[4], g3[4];
      #pragma unroll
      for (int c = 0; c < 4; ++c){
        g0[c] = __ballot(acc[rt][c][r]      < 0);
        g1[c] = __ballot(acc[rt][4 + c][r]  < 0);
        g2[c] = __ballot(acc[rt][8 + c][r]  < 0);
        g3[c] = __ballot(acc[rt][12 + c][r] < 0);
      }
      u64 word = 0;
      #pragma unroll
      for (int c = 0; c < 4; ++c){
        u64 s = pw2 ? (pw1 ? g3[c] : g2[c]) : (pw1 ? g1[c] : g0[c]);
        word |= ((s >> (16*q3)) & 0xFFFFull) << (16*c);
      }
      wreg[rt][r] = word;
    }
  }
  u64 oldv[2][4];
  if (lane < 16){
    #pragma unroll
    for (int rt = 0; rt < 2; ++rt)
      #pragma unroll
      for (int r = 0; r < 4; ++r){
        int row = wv*32 + rt*16 + q3*4 + r;
        oldv[rt][r] = estbits[((long)(b0 + row)*F_ + f)*DW_ + dtp*4 + pw];
      }
  }
  u32 flag = 0;
  if (lane < 16){
    #pragma unroll
    for (int rt = 0; rt < 2; ++rt)
      #pragma unroll
      for (int r = 0; r < 4; ++r){
        int row = wv*32 + rt*16 + q3*4 + r;
        long addr = ((long)(b0 + row)*F_ + f)*DW_ + dtp*4 + pw;
        estbits[addr] = wreg[rt][r];
        flag |= (oldv[rt][r] != wreg[rt][r]) ? 1u : 0u;
      }
  }
  u32 mymiss = (u32)(__ballot(flag != 0) != 0ull);
  if (lane == 0 && mymiss) atomicAnd(&fl->conv[iter], 0u);
}

// final: outcome = argmax_m |sim|, first-occurrence ties (exact integers).
__global__ __launch_bounds__(256) void k_outcome(
    const u64* __restrict__ estbits, const u64* __restrict__ cbbT,
    const Flags* __restrict__ fl, float* __restrict__ out){
  __shared__ u64 es[8][DW_];
  __shared__ int redv[4][8], redi[4][8];
  int f = blockIdx.y, b0 = blockIdx.x * 8;
  int tid = threadIdx.x, wv = tid >> 6, lane = tid & 63;
  for (int idx = tid; idx < 8*DW_; idx += 256){
    int bb = idx >> 7, w = idx & 127;
    es[bb][w] = estbits[((long)(b0 + bb)*F_ + f)*DW_ + w];
  }
  __syncthreads();
  const u64* cbf = cbbT + (long)f*DW_*M_;
  int m0 = tid, m1 = tid + 256;
  int acc0[8], acc1[8];
  #pragma unroll
  for (int bb = 0; bb < 8; ++bb){ acc0[bb] = 0; acc1[bb] = 0; }
  for (int w = 0; w < DW_; ++w){
    u64 c0 = cbf[(long)w*M_ + m0];
    u64 c1 = cbf[(long)w*M_ + m1];
    #pragma unroll
    for (int bb = 0; bb < 8; ++bb){
      u64 e = es[bb][w];
      acc0[bb] += (int)__popcll(e ^ c0);
      acc1[bb] += (int)__popcll(e ^ c1);
    }
  }
  int bv[8], bi[8];
  #pragma unroll
  for (int bb = 0; bb < 8; ++bb){
    int a0 = 4096 - acc0[bb]; if (a0 < 0) a0 = -a0;
    int a1 = 4096 - acc1[bb]; if (a1 < 0) a1 = -a1;
    bv[bb] = a0; bi[bb] = m0;
    if (a1 > a0){ bv[bb] = a1; bi[bb] = m1; }   // tie keeps lower m
  }
  for (int off = 32; off; off >>= 1){
    #pragma unroll
    for (int bb = 0; bb < 8; ++bb){
      int ov = __shfl_xor(bv[bb], off, 64);
      int oi = __shfl_xor(bi[bb], off, 64);
      if (ov > bv[bb] || (ov == bv[bb] && oi < bi[bb])){ bv[bb] = ov; bi[bb] = oi; }
    }
  }
  if (lane == 0)
    #pragma unroll
    for (int bb = 0; bb < 8; ++bb){ redv[wv][bb] = bv[bb]; redi[wv][bb] = bi[bb]; }
  __syncthreads();
  if (tid < 8){
    int v0 = redv[0][tid], i0 = redi[0][tid];
    for (int w = 1; w < 4; ++w){
      int v = redv[w][tid], i = redi[w][tid];
      if (v > v0 || (v == v0 && i < i0)){ v0 = v; i0 = i; }
    }
    out[(long)(b0 + tid)*F_ + f] = (float)i0;
  }
  if (blockIdx.x == 0 && f == 0 && tid == 0){
    int k = ITERS_;
    for (int j = 0; j < ITERS_; ++j) if (fl->conv[j]){ k = j + 1; break; }
    out[B_*F_] = (float)k;
  }
}

__global__ void k_unpack(const u64* __restrict__ estbits, float* __restrict__ out){
  long gid = (long)blockIdx.x*256 + threadIdx.x;   // over B*F*D/4
  int bf = (int)(gid >> 11);
  int d4 = (int)(gid & 2047);
  u64 word = estbits[(long)bf*DW_ + (d4 >> 4)];
  u32 nib = (u32)(word >> ((d4 & 15) * 4)) & 0xFu;
  long base = (long)(B_*F_ + 1) + (long)bf*D_ + (long)d4*4;
  out[base+0] = (nib & 1u) ? -1.0f : 1.0f;
  out[base+1] = (nib & 2u) ? -1.0f : 1.0f;
  out[base+2] = (nib & 4u) ? -1.0f : 1.0f;
  out[base+3] = (nib & 8u) ? -1.0f : 1.0f;
}

extern "C" void kernel_launch(void* const* d_in, const int* in_sizes, int n_in,
                              void* d_out, int out_size, void* d_ws, size_t ws_size,
                              hipStream_t stream){
  const float* input    = (const float*)d_in[0];
  const float* init_est = (const float*)d_in[1];
  const float* cb       = (const float*)d_in[2];
  char* ws   = (char*)d_ws;
  char* outc = (char*)d_out;

  static int s_attr = 0;
  if (!s_attr){
    hipFuncSetAttribute((const void*)k_backward_d256r,
                        hipFuncAttributeMaxDynamicSharedMemorySize, 81920);
    s_attr = 1;
  }

  size_t off = 0;
  Flags* fl = (Flags*)(ws); off = 1024;
  u64* tmp0    = (u64*)(ws + off); off += (size_t)F_*DW_*8;        // 4 KB
  off = (off + 1023) & ~size_t(1023);
  u64* inbits  = (u64*)(ws + off); off += (size_t)B_*DW_*8;        // 1 MB
  u64* estbits = (u64*)(ws + off); off += (size_t)B_*F_*DW_*8;     // 4 MB
  u64* cbbT    = (u64*)(ws + off); off += (size_t)F_*DW_*M_*8;     // 2 MB
  size_t big = (size_t)F_*D_*M_ + 2*(size_t)F_*B_*M_;              // 16 MB + 4 MB
  i8 *cbT8, *Aq, *Ar;
  if (ws_size >= off + big + 1024){
    cbT8 = (i8*)(ws + off); off += (size_t)F_*D_*M_;
    Aq   = (i8*)(ws + off); off += (size_t)F_*B_*M_;
    Ar   = (i8*)(ws + off); off += (size_t)F_*B_*M_;
  } else {
    // d_out is 33558529 float32 = 128.02 MiB; est chunk spans [16388, 134234116).
    // Park scratch high — only the final k_unpack overwrites it, after last use.
    cbT8 = (i8*)(outc + (80ull << 20));    // 80..96 MiB
    Aq   = (i8*)(outc + (100ull << 20));   // 100..102 MiB
    Ar   = (i8*)(outc + (104ull << 20));   // 104..106 MiB
  }

  k_bitify0<<<(F_*D_)/256, 256, 0, stream>>>(init_est, tmp0, fl);
  k_bcast<<<(B_*F_*DW_)/256, 256, 0, stream>>>(tmp0, estbits);
  k_bitify<<<(B_*(long)D_)/256, 256, 0, stream>>>(input, inbits);
  k_cb_prep<<<4096, 256, 0, stream>>>(cb, cbbT, cbT8);

  for (int it = 0; it < ITERS_; ++it){
    k_forward2<<<1024, 256, 0, stream>>>(inbits, estbits, cbbT, Aq, Ar, fl, it);
    k_backward_d256r<<<1024, 256, 81920, stream>>>(Aq, Ar, cbT8, estbits, fl, it);
  }

  k_outcome<<<dim3(B_/8, F_), 256, 0, stream>>>(estbits, cbbT, fl, (float*)d_out);
  k_unpack<<<((long)B_*F_*D_/4)/256, 256, 0, stream>>>(estbits, (float*)d_out);
}